// Round 13
// baseline (812.965 us; speedup 1.0000x reference)
//
#include <hip/hip_runtime.h>
#include <hip/hip_bf16.h>

typedef __attribute__((ext_vector_type(8))) __bf16 bf16x8;
typedef __attribute__((ext_vector_type(4))) float f32x4;

#define N_SEQ   2048
#define N_BATCH 32
#define DIM_U   1024
#define NROWS   65536
#define MA_ELEMS ((size_t)NROWS * DIM_U) /* 67108864 */
#define N_TILES  1024   /* GEMM tiles: 32 batches x 16 mt x 2 nh (batch-major) */
#define N_CHUNKS 1024   /* ma chunks: 64 rows each */

struct Ctl { int tile; int ma; int pad[2]; int bd[32]; int sm[32]; };

__device__ __forceinline__ float tanh_fast(float x) {
    x = fminf(fmaxf(x, -15.f), 15.f);
    float e = __expf(2.f * x);
    return (e - 1.f) * __builtin_amdgcn_rcpf(e + 1.f);
}

// ---------------------------------------------------------------------------
// kernel 0: pack W (1024x512 f32) -> bf16, B-stage order (R5-proven).
__global__ void wpack_kernel(const float* __restrict__ W, __bf16* __restrict__ Wp) {
    int F   = blockIdx.x * 256 + threadIdx.x;   // 0..65535
    int col = F & 255;
    int g   = (F >> 8) & 3;
    int nh  = (F >> 10) & 1;
    int it  = F >> 11;
    int k0  = it * 32 + g * 8;
    int c   = nh * 256 + col;
    bf16x8 o;
#pragma unroll
    for (int j = 0; j < 8; ++j) o[j] = (__bf16)W[(k0 + j) * 512 + c];
    *reinterpret_cast<bf16x8*>(Wp + (size_t)F * 8) = o;
}

// ---------------------------------------------------------------------------
// Shared GEMM-tile macros (R5/R8-proven 2-phase counted-vmcnt schedule).
// Require locals: lds, tid, nh, aglob, awoff, abase0, bbase0, acc, La, Lb.
#define GLD(srcp, dstoff)                                                      \
    __builtin_amdgcn_global_load_lds(                                          \
        (const __attribute__((address_space(1))) void*)(const void*)(srcp),    \
        (__attribute__((address_space(3))) void*)(void*)(lds + (dstoff)), 16, 0, 0)

#define STAGE_B(it_, db_) {                                                    \
        const __bf16* bg_ = Wp + (((size_t)(it_) * 2 + nh) * 1024) * 8;        \
        GLD(bg_ + (size_t)tid * 8,         16384 + (db_) * 16384 + tid * 16);  \
        GLD(bg_ + ((size_t)tid + 512) * 8, 16384 + (db_) * 16384 + 8192 + tid * 16); }

#define LOADA(La_, Lb_, it_) {                                                 \
        const float* p_ = aglob + (it_) * 32;                                  \
        La_ = *reinterpret_cast<const f32x4*>(p_);                             \
        Lb_ = *reinterpret_cast<const f32x4*>(p_ + 4); }

#define CVTW(La_, Lb_, db_) {                                                  \
        bf16x8 pk_ = {(__bf16)La_.x, (__bf16)La_.y, (__bf16)La_.z,             \
                      (__bf16)La_.w, (__bf16)Lb_.x, (__bf16)Lb_.y,             \
                      (__bf16)Lb_.z, (__bf16)Lb_.w};                           \
        *reinterpret_cast<bf16x8*>(lds + (db_) * 8192 + awoff) = pk_; }

#define COMPUTE(db_) {                                                         \
        bf16x8 af[4], bf[4];                                                   \
        _Pragma("unroll")                                                      \
        for (int m = 0; m < 4; ++m)                                            \
            af[m] = *reinterpret_cast<const bf16x8*>(                          \
                lds + (db_) * 8192 + abase0 + m * 256);                        \
        _Pragma("unroll")                                                      \
        for (int n = 0; n < 4; ++n)                                            \
            bf[n] = *reinterpret_cast<const bf16x8*>(                          \
                lds + (db_) * 16384 + bbase0 + n * 256);                       \
        __builtin_amdgcn_s_setprio(1);                                         \
        _Pragma("unroll")                                                      \
        for (int m = 0; m < 4; ++m) {                                          \
            _Pragma("unroll")                                                  \
            for (int n = 0; n < 4; ++n)                                        \
                acc[m][n] = __builtin_amdgcn_mfma_f32_16x16x32_bf16(           \
                    af[m], bf[n], acc[m][n], 0, 0, 0);                         \
        }                                                                      \
        __builtin_amdgcn_s_setprio(0); }

#define WAITBAR2 { asm volatile("s_waitcnt vmcnt(2) lgkmcnt(0)" ::: "memory"); \
                   __builtin_amdgcn_s_barrier(); }
#define WAITBAR0 { asm volatile("s_waitcnt vmcnt(0) lgkmcnt(0)" ::: "memory"); \
                   __builtin_amdgcn_s_barrier(); }

// Full GEMM tile body (prologue + 32 iters + epilogue writing sp).
#define GEMM_TILE_BODY                                                         \
    f32x4 acc[4][4];                                                           \
    _Pragma("unroll")                                                          \
    for (int m = 0; m < 4; ++m)                                                \
        _Pragma("unroll")                                                      \
        for (int n = 0; n < 4; ++n) acc[m][n] = f32x4{0.f, 0.f, 0.f, 0.f};     \
    f32x4 La, Lb;                                                              \
    LOADA(La, Lb, 0);                                                          \
    CVTW(La, Lb, 0);                                                           \
    STAGE_B(0, 0);                                                             \
    __builtin_amdgcn_sched_barrier(0);                                         \
    f32x4 L1a, L1b;                                                            \
    LOADA(L1a, L1b, 1);                                                        \
    __builtin_amdgcn_sched_barrier(0);                                         \
    WAITBAR2;                                                                  \
    for (int tt = 0; tt < 15; ++tt) {                                          \
        const int t0 = 2 * tt;                                                 \
        STAGE_B(t0 + 1, 1);                                                    \
        __builtin_amdgcn_sched_barrier(0);                                     \
        LOADA(La, Lb, t0 + 2);                                                 \
        __builtin_amdgcn_sched_barrier(0);                                     \
        COMPUTE(0);                                                            \
        CVTW(L1a, L1b, 1);                                                     \
        WAITBAR2;                                                              \
        STAGE_B(t0 + 2, 0);                                                    \
        __builtin_amdgcn_sched_barrier(0);                                     \
        LOADA(L1a, L1b, t0 + 3);                                               \
        __builtin_amdgcn_sched_barrier(0);                                     \
        COMPUTE(1);                                                            \
        CVTW(La, Lb, 0);                                                       \
        WAITBAR2;                                                              \
    }                                                                          \
    STAGE_B(31, 1);                                                            \
    COMPUTE(0);                                                                \
    CVTW(L1a, L1b, 1);                                                         \
    WAITBAR0;                                                                  \
    COMPUTE(1);                                                                \
    float bias[4], uu[4];                                                      \
    _Pragma("unroll")                                                          \
    for (int n = 0; n < 4; ++n) {                                              \
        int col = nh * 256 + wc * 64 + n * 16 + c15;                           \
        bias[n] = Bb[col];                                                     \
        uu[n]   = Uv[col];                                                     \
    }                                                                          \
    float* partial = reinterpret_cast<float*>(lds);                            \
    _Pragma("unroll")                                                          \
    for (int m = 0; m < 4; ++m) {                                              \
        float pr[4];                                                           \
        _Pragma("unroll")                                                      \
        for (int r = 0; r < 4; ++r) pr[r] = 0.f;                               \
        _Pragma("unroll")                                                      \
        for (int n = 0; n < 4; ++n)                                            \
            _Pragma("unroll")                                                  \
            for (int r = 0; r < 4; ++r)                                        \
                pr[r] += tanh_fast(acc[m][n][r] + bias[n]) * uu[n];            \
        _Pragma("unroll")                                                      \
        for (int r = 0; r < 4; ++r) {                                          \
            float v = pr[r];                                                   \
            v += __shfl_xor(v, 1); v += __shfl_xor(v, 2);                      \
            v += __shfl_xor(v, 4); v += __shfl_xor(v, 8);                      \
            if (c15 == 0)                                                      \
                partial[wc * 128 + wr * 64 + m * 16 + hi * 4 + r] = v;         \
        }                                                                      \
    }                                                                          \
    __syncthreads();                                                           \
    if (tid < 128) {                                                           \
        float sc = (partial[tid] + partial[128 + tid]) +                       \
                   (partial[256 + tid] + partial[384 + tid]);                  \
        sp[(size_t)nh * NROWS + rowbase + tid] = sc;                           \
    }

// ---------------------------------------------------------------------------
// Fused kernel: producers (GEMM tiles, dynamic claim, batch-major; last
// finisher of a batch runs its softmax inline) + consumers (ma chunks, gated
// on per-batch smDone flags). Deadlock-free: resident capacity (2 blocks/CU
// x 256 = 512) exceeds consumer count (256), so producers always progress;
// all claimed tiles belong to resident blocks. Cross-XCD visibility:
// stores -> __syncthreads (vmcnt drain) -> __threadfence (device wb/inv) ->
// device-scope atomic; readers poll atomic then __threadfence then read.
__global__ __launch_bounds__(512, 4) void fused_kernel(
    const float* __restrict__ H, const __bf16* __restrict__ Wp,
    const float* __restrict__ Bb, const float* __restrict__ Uv,
    float* __restrict__ sp, float* __restrict__ VU, float* __restrict__ Ma,
    Ctl* ctl)
{
    __shared__ __align__(16) char lds[49152];
    __shared__ int s_t;
    __shared__ int s_last;
    __shared__ float red[16];

    const int tid  = threadIdx.x;
    const int lane = tid & 63;
    const int wid  = tid >> 6;
    const int c15  = lane & 15;
    const int hi   = lane >> 4;
    const int wr   = wid >> 2;
    const int wc   = wid & 3;
    const int bid  = blockIdx.x;
    const bool consumer = ((bid & 3) == 3) && (bid < 1024);

    // frag/staging offsets (tile-independent)
    const int arow = tid >> 2, ag = tid & 3;
    const int awoff  = ag * 2048 + ((arow ^ ag) * 16);
    const int abase0 = hi * 2048 + (wr * 64 + (c15 ^ hi)) * 16;
    const int bbase0 = 16384 + hi * 4096 + (wc * 64 + c15) * 16;

    if (!consumer) {
        // ================= producer: GEMM tiles =================
        for (;;) {
            __syncthreads();
            if (tid == 0) s_t = atomicAdd(&ctl->tile, 1);
            __syncthreads();
            const int t = s_t;
            if (t >= N_TILES) break;

            const int b  = t >> 5;           // batch (batch-major claim order)
            const int j  = t & 31;
            const int mt = (b << 4) + (j >> 1);
            const int nh = j & 1;
            const long rowbase = (long)mt * 128;
            const float* aglob = H + (rowbase + arow) * DIM_U + ag * 8;

            GEMM_TILE_BODY;

            __syncthreads();                 // all sp stores drained to L2
            __threadfence();                 // L2 writeback (device scope)
            if (tid == 0) {
                int old = atomicAdd(&ctl->bd[b], 1);
                s_last = (old == 31);
            }
            __syncthreads();
            if (s_last) {
                __threadfence();             // acquire other tiles' sp
                // softmax for batch b over n=2048 (4 values/thread)
                float v[4];
                float mx = -3.0e38f;
#pragma unroll
                for (int q = 0; q < 4; ++q) {
                    int x = b * N_SEQ + tid + q * 512;
                    v[q] = sp[x] + sp[NROWS + x];
                    mx = fmaxf(mx, v[q]);
                }
#pragma unroll
                for (int off = 1; off < 64; off <<= 1)
                    mx = fmaxf(mx, __shfl_xor(mx, off));
                if (lane == 0) red[wid] = mx;
                __syncthreads();
                mx = fmaxf(fmaxf(fmaxf(red[0], red[1]), fmaxf(red[2], red[3])),
                           fmaxf(fmaxf(red[4], red[5]), fmaxf(red[6], red[7])));
                float e[4], sum = 0.f;
#pragma unroll
                for (int q = 0; q < 4; ++q) { e[q] = __expf(v[q] - mx); sum += e[q]; }
#pragma unroll
                for (int off = 1; off < 64; off <<= 1) sum += __shfl_xor(sum, off);
                if (lane == 0) red[8 + wid] = sum;
                __syncthreads();
                float total = ((red[8] + red[9]) + (red[10] + red[11])) +
                              ((red[12] + red[13]) + (red[14] + red[15]));
                float rinv = 1.f / total;
#pragma unroll
                for (int q = 0; q < 4; ++q)
                    VU[b * N_SEQ + tid + q * 512] = e[q] * rinv;
                __syncthreads();             // VU stores drained
                __threadfence();             // release
                if (tid == 0) atomicExch(&ctl->sm[b], 1);
            }
        }
        // fall through: help with ma after the tile queue empties
    }

    // ================= consumer: ma chunks (64 rows each) =================
    const f32x4* Hv  = reinterpret_cast<const f32x4*>(H);
    f32x4*       Mav = reinterpret_cast<f32x4*>(Ma);
    for (;;) {
        __syncthreads();
        if (tid == 0) s_t = atomicAdd(&ctl->ma, 1);
        __syncthreads();
        const int m = s_t;
        if (m >= N_CHUNKS) break;
        const int bt = m >> 5;               // 32 chunks per batch
        if (tid == 0) {
            while (atomicAdd(&ctl->sm[bt], 0) == 0) __builtin_amdgcn_s_sleep(16);
        }
        __syncthreads();
        __threadfence();                     // acquire VU (+ nothing else needed)
        const long r0 = (long)m * 64;
#pragma unroll 4
        for (int k = 0; k < 32; ++k) {
            const int flat = tid + k * 512;          // 0..16383 f32x4 slots
            const long row = r0 + (flat >> 8);
            const float sc = VU[row];
            f32x4 h = Hv[row * 256 + (flat & 255)];
            __builtin_nontemporal_store(h * sc, Mav + row * 256 + (flat & 255));
        }
    }
}

// ---------------------------------------------------------------------------
// Fallback path kernels (R12-proven): used when ws is too small.
__global__ __launch_bounds__(512, 4) void score_gemm_kernel(
    const float* __restrict__ H, const __bf16* __restrict__ Wp,
    const float* __restrict__ Bb, const float* __restrict__ Uv,
    float* __restrict__ sp)
{
    __shared__ __align__(16) char lds[49152];
    const int tid  = threadIdx.x;
    const int lane = tid & 63;
    const int wid  = tid >> 6;
    const int c15  = lane & 15;
    const int hi   = lane >> 4;
    const int wr   = wid >> 2;
    const int wc   = wid & 3;
    const int bid = blockIdx.x;
    const int L   = (bid & 7) * 128 + (bid >> 3);
    const int mt = L >> 1, nh = L & 1;
    const long rowbase = (long)mt * 128;
    const int arow = tid >> 2, ag = tid & 3;
    const float* aglob = H + (rowbase + arow) * DIM_U + ag * 8;
    const int awoff  = ag * 2048 + ((arow ^ ag) * 16);
    const int abase0 = hi * 2048 + (wr * 64 + (c15 ^ hi)) * 16;
    const int bbase0 = 16384 + hi * 4096 + (wc * 64 + c15) * 16;
    GEMM_TILE_BODY;
}

__global__ void softmax_kernel(const float* __restrict__ sp, float* __restrict__ VU) {
    __shared__ float red[8];
    const int b = blockIdx.x, tid = threadIdx.x;
    const int lane = tid & 63, wid = tid >> 6;
    float v[8];
    float mx = -3.0e38f;
#pragma unroll
    for (int j = 0; j < 8; ++j) {
        int x = b * N_SEQ + tid + j * 256;
        v[j] = sp[x] + sp[NROWS + x];
        mx = fmaxf(mx, v[j]);
    }
#pragma unroll
    for (int off = 1; off < 64; off <<= 1) mx = fmaxf(mx, __shfl_xor(mx, off));
    if (lane == 0) red[wid] = mx;
    __syncthreads();
    mx = fmaxf(fmaxf(red[0], red[1]), fmaxf(red[2], red[3]));
    float e[8], sum = 0.f;
#pragma unroll
    for (int j = 0; j < 8; ++j) { e[j] = __expf(v[j] - mx); sum += e[j]; }
#pragma unroll
    for (int off = 1; off < 64; off <<= 1) sum += __shfl_xor(sum, off);
    if (lane == 0) red[4 + wid] = sum;
    __syncthreads();
    float total = (red[4] + red[5]) + (red[6] + red[7]);
    float rinv = 1.f / total;
#pragma unroll
    for (int j = 0; j < 8; ++j) VU[b * N_SEQ + tid + j * 256] = e[j] * rinv;
}

__global__ void ma_kernel(const float* __restrict__ H, const float* __restrict__ VU,
                          float* __restrict__ Ma) {
    const int b = blockIdx.x;
    const int s = b & 7, j = b >> 3;
    const long row0 = (long)s * 8192 + (long)(255 - j) * 32;
    const int tid = threadIdx.x;
    const float* h = H + row0 * DIM_U;
    float*       o = Ma + row0 * DIM_U;
#pragma unroll 4
    for (int r = 0; r < 32; ++r) {
        float sc = VU[row0 + r];
        f32x4 hv = reinterpret_cast<const f32x4*>(h + (size_t)r * DIM_U)[tid];
        __builtin_nontemporal_store(hv * sc,
            reinterpret_cast<f32x4*>(o + (size_t)r * DIM_U) + tid);
    }
}

// ---------------------------------------------------------------------------
extern "C" void kernel_launch(void* const* d_in, const int* in_sizes, int n_in,
                              void* d_out, int out_size, void* d_ws, size_t ws_size,
                              hipStream_t stream) {
    const float* H  = (const float*)d_in[0];
    const float* W  = (const float*)d_in[1];
    const float* Bb = (const float*)d_in[2];
    const float* Uv = (const float*)d_in[3];

    float* out = (float*)d_out;
    float* Ma  = out;                          // 67108864 floats
    float* VU  = out + MA_ELEMS;               // 65536 floats (output VU)

    if (ws_size >= (size_t)4 * 1024 * 1024) {
        // ws layout: [0,1KB) Ctl  [1KB,513KB) sp  [1MB,2MB) Wp
        char* ws = (char*)d_ws;
        Ctl*    ctl = (Ctl*)ws;
        float*  sp  = (float*)(ws + 1024);
        __bf16* Wp  = (__bf16*)(ws + 1048576);
        hipMemsetAsync(ws, 0, 1024, stream);   // zero counters each call
        wpack_kernel<<<256, 256, 0, stream>>>(W, Wp);
        fused_kernel<<<1280, 512, 0, stream>>>(H, Wp, Bb, Uv, sp, VU, Ma, ctl);
    } else {
        // R12 fallback: scratch aliased inside the Ma region
        float*  sp = out;                      // 2 x 65536 partials
        __bf16* Wp = (__bf16*)(out + 131072);  // 1MB
        wpack_kernel<<<256, 256, 0, stream>>>(W, Wp);
        score_gemm_kernel<<<1024, 512, 0, stream>>>(H, Wp, Bb, Uv, sp);
        softmax_kernel<<<N_BATCH, 256, 0, stream>>>(sp, VU);
        ma_kernel<<<2048, 256, 0, stream>>>(H, VU, Ma);
    }
}

// Round 14
// 163.236 us; speedup vs baseline: 4.9803x; 4.9803x over previous
//
#include <hip/hip_runtime.h>
#include <hip/hip_bf16.h>

typedef __attribute__((ext_vector_type(8))) __bf16 bf16x8;
typedef __attribute__((ext_vector_type(4))) float f32x4;

#define N_SEQ   2048
#define N_BATCH 32
#define DIM_U   1024
#define NROWS   65536
#define MA_ELEMS ((size_t)NROWS * DIM_U) /* 67108864 */

__device__ __forceinline__ float tanh_fast(float x) {
    x = fminf(fmaxf(x, -15.f), 15.f);
    float e = __expf(2.f * x);
    return (e - 1.f) * __builtin_amdgcn_rcpf(e + 1.f);
}

// ---------------------------------------------------------------------------
// kernel 0: pack W (1024x512 f32) -> bf16, B-stage order.
// F = ((it*2+nh)*4+g)*256+col; elem j: k=it*32+g*8+j, c=nh*256+col.
// Chunk (it,nh) = 1024 groups = 16KB = one LDS B-slab [g][col256][16B].
__global__ void wpack_kernel(const float* __restrict__ W, __bf16* __restrict__ Wp) {
    int F   = blockIdx.x * 256 + threadIdx.x;   // 0..65535
    int col = F & 255;
    int g   = (F >> 8) & 3;
    int nh  = (F >> 10) & 1;
    int it  = F >> 11;
    int k0  = it * 32 + g * 8;
    int c   = nh * 256 + col;
    bf16x8 o;
#pragma unroll
    for (int j = 0; j < 8; ++j) o[j] = (__bf16)W[(k0 + j) * 512 + c];
    *reinterpret_cast<bf16x8*>(Wp + (size_t)F * 8) = o;
}

// ---------------------------------------------------------------------------
// kernel 1 (R5/R8-proven): partial scores. WG = 128 rows x 256 cols, BK=32,
// 32 iters. 8 waves (2M x 4N), wave 64x64. LDS 48KB: A dbuf 2x8KB XOR-swz,
// B dbuf 2x16KB via gload_lds. One barrier/iter, counted vmcnt(2).
// 2 blocks/CU anti-phase covers the barrier stalls (R13 lesson: this pairing
// is load-bearing -- heterogeneous co-residents collapse it 5x).
__global__ __launch_bounds__(512, 4) void score_gemm_kernel(
    const float* __restrict__ H, const __bf16* __restrict__ Wp,
    const float* __restrict__ Bb, const float* __restrict__ Uv,
    float* __restrict__ sp)
{
    __shared__ __align__(16) char lds[49152];
    const int tid  = threadIdx.x;
    const int lane = tid & 63;
    const int wid  = tid >> 6;     // 0..7
    const int c15  = lane & 15;
    const int hi   = lane >> 4;    // 0..3
    const int wr   = wid >> 2;     // 0..1 (M)
    const int wc   = wid & 3;      // 0..3 (N)

    // XCD-bijective swizzle: segment s = bid&7 covers H rows [s*8192,(s+1)*8192)
    const int bid = blockIdx.x;
    const int L   = (bid & 7) * 128 + (bid >> 3);
    const int mt = L >> 1, nh = L & 1;
    const long rowbase = (long)mt * 128;

    // A staging: thread covers row=tid>>2, g=tid&3 (8 f32 -> 1 bf16x8)
    const int arow = tid >> 2, ag = tid & 3;
    const float* aglob = H + (rowbase + arow) * DIM_U + ag * 8;
    const int awoff = ag * 2048 + ((arow ^ ag) * 16);      // + db*8192

    // frag read bases
    const int abase0 = hi * 2048 + (wr * 64 + (c15 ^ hi)) * 16;   // + db*8192 + m*256
    const int bbase0 = 16384 + hi * 4096 + (wc * 64 + c15) * 16;  // + db*16384 + n*256

#define GLD(srcp, dstoff)                                                      \
    __builtin_amdgcn_global_load_lds(                                          \
        (const __attribute__((address_space(1))) void*)(const void*)(srcp),    \
        (__attribute__((address_space(3))) void*)(void*)(lds + (dstoff)), 16, 0, 0)

#define STAGE_B(it_, db_) {                                                    \
        const __bf16* bg_ = Wp + (((size_t)(it_) * 2 + nh) * 1024) * 8;        \
        GLD(bg_ + (size_t)tid * 8,         16384 + (db_) * 16384 + tid * 16);  \
        GLD(bg_ + ((size_t)tid + 512) * 8, 16384 + (db_) * 16384 + 8192 + tid * 16); }

#define LOADA(La_, Lb_, it_) {                                                 \
        const float* p_ = aglob + (it_) * 32;                                  \
        La_ = *reinterpret_cast<const f32x4*>(p_);                             \
        Lb_ = *reinterpret_cast<const f32x4*>(p_ + 4); }

#define CVTW(La_, Lb_, db_) {                                                  \
        bf16x8 pk_ = {(__bf16)La_.x, (__bf16)La_.y, (__bf16)La_.z,             \
                      (__bf16)La_.w, (__bf16)Lb_.x, (__bf16)Lb_.y,             \
                      (__bf16)Lb_.z, (__bf16)Lb_.w};                           \
        *reinterpret_cast<bf16x8*>(lds + (db_) * 8192 + awoff) = pk_; }

#define COMPUTE(db_) {                                                         \
        bf16x8 af[4], bf[4];                                                   \
        _Pragma("unroll")                                                      \
        for (int m = 0; m < 4; ++m)                                            \
            af[m] = *reinterpret_cast<const bf16x8*>(                          \
                lds + (db_) * 8192 + abase0 + m * 256);                        \
        _Pragma("unroll")                                                      \
        for (int n = 0; n < 4; ++n)                                            \
            bf[n] = *reinterpret_cast<const bf16x8*>(                          \
                lds + (db_) * 16384 + bbase0 + n * 256);                       \
        __builtin_amdgcn_s_setprio(1);                                         \
        _Pragma("unroll")                                                      \
        for (int m = 0; m < 4; ++m) {                                          \
            _Pragma("unroll")                                                  \
            for (int n = 0; n < 4; ++n)                                        \
                acc[m][n] = __builtin_amdgcn_mfma_f32_16x16x32_bf16(           \
                    af[m], bf[n], acc[m][n], 0, 0, 0);                         \
        }                                                                      \
        __builtin_amdgcn_s_setprio(0); }

#define WAITBAR2 { asm volatile("s_waitcnt vmcnt(2) lgkmcnt(0)" ::: "memory"); \
                   __builtin_amdgcn_s_barrier(); }
#define WAITBAR0 { asm volatile("s_waitcnt vmcnt(0) lgkmcnt(0)" ::: "memory"); \
                   __builtin_amdgcn_s_barrier(); }

    f32x4 acc[4][4];
#pragma unroll
    for (int m = 0; m < 4; ++m)
#pragma unroll
        for (int n = 0; n < 4; ++n) acc[m][n] = f32x4{0.f, 0.f, 0.f, 0.f};

    f32x4 L0a, L0b, L1a, L1b;

    // ---- prologue: A(0)+B(0) -> buf0; A(1) in flight
    LOADA(L0a, L0b, 0);
    CVTW(L0a, L0b, 0);                  // compiler waits on L0 here
    STAGE_B(0, 0);
    __builtin_amdgcn_sched_barrier(0);
    LOADA(L1a, L1b, 1);
    __builtin_amdgcn_sched_barrier(0);
    WAITBAR2;                            // B(0) landed; A(1) flying

    // ---- main loop: iters 0..29 (pairs), peeled 30/31
    for (int tt = 0; tt < 15; ++tt) {
        const int t0 = 2 * tt;
        // even iter t0: read buf0, stage buf1
        STAGE_B(t0 + 1, 1);
        __builtin_amdgcn_sched_barrier(0);
        LOADA(L0a, L0b, t0 + 2);
        __builtin_amdgcn_sched_barrier(0);
        COMPUTE(0);
        CVTW(L1a, L1b, 1);               // A(t0+1)
        WAITBAR2;
        // odd iter t0+1: read buf1, stage buf0
        STAGE_B(t0 + 2, 0);
        __builtin_amdgcn_sched_barrier(0);
        LOADA(L1a, L1b, t0 + 3);
        __builtin_amdgcn_sched_barrier(0);
        COMPUTE(1);
        CVTW(L0a, L0b, 0);               // A(t0+2)
        WAITBAR2;
    }
    // iter 30 (reads buf0, stages buf1)
    STAGE_B(31, 1);
    COMPUTE(0);
    CVTW(L1a, L1b, 1);                   // A(31)
    WAITBAR0;
    // iter 31 (reads buf1)
    COMPUTE(1);

    // ---- epilogue: tanh(acc + bias)*U, reduce over the WG's 256 cols
    float bias[4], uu[4];
#pragma unroll
    for (int n = 0; n < 4; ++n) {
        int col = nh * 256 + wc * 64 + n * 16 + c15;
        bias[n] = Bb[col];
        uu[n]   = Uv[col];
    }
    float* partial = reinterpret_cast<float*>(lds);  // [4 wc][128 rows]
#pragma unroll
    for (int m = 0; m < 4; ++m) {
        float pr[4];
#pragma unroll
        for (int r = 0; r < 4; ++r) pr[r] = 0.f;
#pragma unroll
        for (int n = 0; n < 4; ++n)
#pragma unroll
            for (int r = 0; r < 4; ++r)
                pr[r] += tanh_fast(acc[m][n][r] + bias[n]) * uu[n];
#pragma unroll
        for (int r = 0; r < 4; ++r) {
            float v = pr[r];
            v += __shfl_xor(v, 1); v += __shfl_xor(v, 2);
            v += __shfl_xor(v, 4); v += __shfl_xor(v, 8);
            if (c15 == 0)
                partial[wc * 128 + wr * 64 + m * 16 + hi * 4 + r] = v;
        }
    }
    __syncthreads();
    if (tid < 128) {
        float sc = (partial[tid] + partial[128 + tid]) +
                   (partial[256 + tid] + partial[384 + tid]);
        sp[(size_t)nh * NROWS + rowbase + tid] = sc;
    }
}

// ---------------------------------------------------------------------------
// kernel 2: per-batch softmax over n=2048 (scores = sum of 2 N-partials)
__global__ void softmax_kernel(const float* __restrict__ sp, float* __restrict__ VU) {
    __shared__ float red[8];
    const int b = blockIdx.x, tid = threadIdx.x;
    const int lane = tid & 63, wid = tid >> 6;
    float v[8];
    float mx = -3.0e38f;
#pragma unroll
    for (int j = 0; j < 8; ++j) {
        int x = b * N_SEQ + tid + j * 256;
        v[j] = sp[x] + sp[NROWS + x];
        mx = fmaxf(mx, v[j]);
    }
#pragma unroll
    for (int off = 1; off < 64; off <<= 1) mx = fmaxf(mx, __shfl_xor(mx, off));
    if (lane == 0) red[wid] = mx;
    __syncthreads();
    mx = fmaxf(fmaxf(red[0], red[1]), fmaxf(red[2], red[3]));
    float e[8], sum = 0.f;
#pragma unroll
    for (int j = 0; j < 8; ++j) { e[j] = __expf(v[j] - mx); sum += e[j]; }
#pragma unroll
    for (int off = 1; off < 64; off <<= 1) sum += __shfl_xor(sum, off);
    if (lane == 0) red[4 + wid] = sum;
    __syncthreads();
    float total = (red[4] + red[5]) + (red[6] + red[7]);
    float rinv = 1.f / total;
#pragma unroll
    for (int j = 0; j < 8; ++j) VU[b * N_SEQ + tid + j * 256] = e[j] * rinv;
}

// ---------------------------------------------------------------------------
// kernel 3: Ma = H * VU, reverse-streamed per XCD segment for L3 reuse
// (reads start where the GEMM's reads ended). NT stores keep the Ma write
// stream from evicting H.
__global__ void ma_kernel(const float* __restrict__ H, const float* __restrict__ VU,
                          float* __restrict__ Ma) {
    const int b = blockIdx.x;                    // 0..2047
    const int s = b & 7, j = b >> 3;             // segment, chunk-in-segment
    const long row0 = (long)s * 8192 + (long)(255 - j) * 32;
    const int tid = threadIdx.x;                 // 256 thr: one f32x4 per row
    const float* h = H + row0 * DIM_U;
    float*       o = Ma + row0 * DIM_U;
#pragma unroll 4
    for (int r = 0; r < 32; ++r) {
        float sc = VU[row0 + r];                 // uniform -> s_load
        f32x4 hv = reinterpret_cast<const f32x4*>(h + (size_t)r * DIM_U)[tid];
        __builtin_nontemporal_store(hv * sc,
            reinterpret_cast<f32x4*>(o + (size_t)r * DIM_U) + tid);
    }
}

// ---------------------------------------------------------------------------
extern "C" void kernel_launch(void* const* d_in, const int* in_sizes, int n_in,
                              void* d_out, int out_size, void* d_ws, size_t ws_size,
                              hipStream_t stream) {
    const float* H  = (const float*)d_in[0];
    const float* W  = (const float*)d_in[1];
    const float* Bb = (const float*)d_in[2];
    const float* Uv = (const float*)d_in[3];

    float* out = (float*)d_out;
    float* Ma  = out;                          // 67108864 floats
    float* VU  = out + MA_ELEMS;               // 65536 floats
    // scratch inside the Ma region (ma_kernel overwrites it all at the end):
    float*  sp = out;                          // 2 x 65536 partial scores
    __bf16* Wp = (__bf16*)(out + 131072);      // 524288 bf16 (1MB)

    wpack_kernel<<<256, 256, 0, stream>>>(W, Wp);
    score_gemm_kernel<<<1024, 512, 0, stream>>>(H, Wp, Bb, Uv, sp);
    softmax_kernel<<<N_BATCH, 256, 0, stream>>>(sp, VU);
    ma_kernel<<<2048, 256, 0, stream>>>(H, VU, Ma);
}